// Round 1
// baseline (278.084 us; speedup 1.0000x reference)
//
#include <hip/hip_runtime.h>
#include <math.h>

constexpr int BATCH  = 2;
constexpr int LSEQ   = 4096;
constexpr int DMODEL = 256;
constexpr int DINNER = 512;
constexpr int NPROJ  = 2 * DINNER;      // 1024
constexpr int NST    = 16;              // d_state
constexpr int MROWS  = BATCH * LSEQ;    // 8192
constexpr int NCH    = 128;             // chunks per sequence
constexpr int TCH    = LSEQ / NCH;      // 32 steps per chunk
constexpr float LOG2E = 1.44269504088896f;

__device__ __forceinline__ float fast_silu(float v) { return v / (1.f + __expf(-v)); }

// ---------------------------------------------------------------- K1: xz = x @ in_proj_w, split u/z
__global__ __launch_bounds__(256) void k_inproj(const float* __restrict__ X,
                                                const float* __restrict__ W,
                                                float* __restrict__ u,
                                                float* __restrict__ z) {
  __shared__ float As[64][33];
  __shared__ float Bs[32][64];
  const int t  = threadIdx.x;
  const int m0 = (blockIdx.x & 127) * 64;   // M/64 = 128
  const int n0 = (blockIdx.x >> 7) * 64;    // N/64 = 16
  const int tm = t >> 4, tn = t & 15;
  float acc[4][4] = {};
  for (int k0 = 0; k0 < DMODEL; k0 += 32) {
    // A tile 64x32 (two float4 per thread)
    {
      int v = t;
      int row = v >> 3, c4 = v & 7;
      float4 a = *(const float4*)(X + (m0 + row) * DMODEL + k0 + c4 * 4);
      As[row][c4*4+0] = a.x; As[row][c4*4+1] = a.y; As[row][c4*4+2] = a.z; As[row][c4*4+3] = a.w;
      v = t + 256; row = v >> 3; c4 = v & 7;
      a = *(const float4*)(X + (m0 + row) * DMODEL + k0 + c4 * 4);
      As[row][c4*4+0] = a.x; As[row][c4*4+1] = a.y; As[row][c4*4+2] = a.z; As[row][c4*4+3] = a.w;
    }
    // B tile 32x64
    {
      int v = t;
      int row = v >> 4, c4 = v & 15;
      *(float4*)(&Bs[row][c4*4]) = *(const float4*)(W + (k0 + row) * NPROJ + n0 + c4 * 4);
      v = t + 256; row = v >> 4; c4 = v & 15;
      *(float4*)(&Bs[row][c4*4]) = *(const float4*)(W + (k0 + row) * NPROJ + n0 + c4 * 4);
    }
    __syncthreads();
    #pragma unroll
    for (int k = 0; k < 32; ++k) {
      float av[4];
      #pragma unroll
      for (int i = 0; i < 4; ++i) av[i] = As[tm * 4 + i][k];
      float4 bv = *(const float4*)(&Bs[k][tn * 4]);
      float bj[4] = {bv.x, bv.y, bv.z, bv.w};
      #pragma unroll
      for (int i = 0; i < 4; ++i)
        #pragma unroll
        for (int j = 0; j < 4; ++j) acc[i][j] = fmaf(av[i], bj[j], acc[i][j]);
    }
    __syncthreads();
  }
  #pragma unroll
  for (int i = 0; i < 4; ++i) {
    int m = m0 + tm * 4 + i;
    #pragma unroll
    for (int j = 0; j < 4; ++j) {
      int n = n0 + tn * 4 + j;
      if (n < DINNER) u[m * DINNER + n] = acc[i][j];
      else            z[m * DINNER + (n - DINNER)] = acc[i][j];
    }
  }
}

// ---------------------------------------------------------------- K2: depthwise causal conv + SiLU
__global__ __launch_bounds__(256) void k_conv(const float* __restrict__ u,
                                              const float* __restrict__ cw,
                                              const float* __restrict__ cb,
                                              float* __restrict__ uc) {
  const int idx = blockIdx.x * 256 + threadIdx.x;    // m*DINNER + d
  const int d = idx & (DINNER - 1);
  const int m = idx >> 9;
  const int l = m & (LSEQ - 1);
  float acc = cb[d];
  #pragma unroll
  for (int j = 0; j < 4; ++j) {
    int lj = l + j - 3;
    float uu = (lj >= 0) ? u[idx + (j - 3) * DINNER] : 0.f;
    acc = fmaf(uu, cw[d * 4 + j], acc);
  }
  uc[idx] = fast_silu(acc);
}

// ---------------------------------------------------------------- K3a: dbl = u_conv @ x_proj_w -> dt,B,C
__global__ __launch_bounds__(256) void k_xproj(const float* __restrict__ uc,
                                               const float* __restrict__ xpw,
                                               float* __restrict__ dt_out,
                                               float* __restrict__ Bout,
                                               float* __restrict__ Cout) {
  const int idx = blockIdx.x * 256 + threadIdx.x;    // m*48 + j
  const int j = idx % 48;
  const int m = idx / 48;
  const float* row = uc + m * DINNER;
  const float* wc  = xpw + j;
  float a0 = 0.f, a1 = 0.f, a2 = 0.f, a3 = 0.f;
  for (int k = 0; k < DINNER; k += 4) {
    a0 = fmaf(row[k + 0], wc[(k + 0) * 48], a0);
    a1 = fmaf(row[k + 1], wc[(k + 1) * 48], a1);
    a2 = fmaf(row[k + 2], wc[(k + 2) * 48], a2);
    a3 = fmaf(row[k + 3], wc[(k + 3) * 48], a3);
  }
  float acc = (a0 + a1) + (a2 + a3);
  if (j < 16)       dt_out[m * 16 + j]      = acc;
  else if (j < 32)  Bout[m * 16 + (j - 16)] = acc;
  else              Cout[m * 16 + (j - 32)] = acc;
}

// ---------------------------------------------------------------- K3b: delta = softplus(dt @ dt_proj_w + b)
__global__ __launch_bounds__(256) void k_delta(const float* __restrict__ dtin,
                                               const float* __restrict__ dtw,
                                               const float* __restrict__ dtbias,
                                               float* __restrict__ delta) {
  const int idx = blockIdx.x * 256 + threadIdx.x;    // m*DINNER + d
  const int d = idx & (DINNER - 1);
  const int m = idx >> 9;
  float acc = dtbias[d];
  const float* dr = dtin + m * 16;
  #pragma unroll
  for (int r = 0; r < 16; ++r) acc = fmaf(dr[r], dtw[r * DINNER + d], acc);
  delta[idx] = (acc > 20.f) ? acc : log1pf(__expf(acc));
}

// ---------------------------------------------------------------- K4a: chunked scan pass 1 (per-chunk S, sum delta)
__global__ __launch_bounds__(256) void k_scan1(const float* __restrict__ delta,
                                               const float* __restrict__ uc,
                                               const float* __restrict__ Bin,
                                               const float* __restrict__ Alog,
                                               float* __restrict__ Ssum,
                                               float* __restrict__ Dsum) {
  const int g = blockIdx.x * 256 + threadIdx.x;      // (b*NCH + c)*DINNER + d
  const int d    = g & (DINNER - 1);
  const int rest = g >> 9;
  const int c = rest & (NCH - 1);
  const int b = rest >> 7;
  __shared__ float Bsh[TCH][NST];
  {
    const int base = (b * LSEQ + c * TCH) * NST;
    for (int v = threadIdx.x; v < TCH * NST; v += 256) ((float*)Bsh)[v] = Bin[base + v];
  }
  __syncthreads();
  float a2[NST];
  #pragma unroll
  for (int n = 0; n < NST; ++n) a2[n] = -__expf(Alog[d * NST + n]) * LOG2E;
  float S[NST];
  #pragma unroll
  for (int n = 0; n < NST; ++n) S[n] = 0.f;
  float dsum = 0.f;
  const int row0 = (b * LSEQ + c * TCH) * DINNER + d;
  for (int tt = 0; tt < TCH; ++tt) {
    float de = delta[row0 + tt * DINNER];
    float xv = uc[row0 + tt * DINNER];
    float du = de * xv;
    dsum += de;
    #pragma unroll
    for (int n = 0; n < NST; ++n) {
      float dA = exp2f(de * a2[n]);                 // exp(delta * A[d][n])
      S[n] = fmaf(dA, S[n], du * Bsh[tt][n]);
    }
  }
  const int cidx = (b * DINNER + d) * NCH + c;
  Dsum[cidx] = dsum;
  #pragma unroll
  for (int n = 0; n < NST; ++n) Ssum[cidx * NST + n] = S[n];
}

// ---------------------------------------------------------------- K4b: cross-chunk exclusive scan
__global__ void k_scan2(const float* __restrict__ Ssum,
                        const float* __restrict__ Dsum,
                        const float* __restrict__ Alog,
                        float* __restrict__ Hinit) {
  const int g = blockIdx.x * 256 + threadIdx.x;      // (b*DINNER + d)*NST + n
  const int n  = g & (NST - 1);
  const int bd = g >> 4;
  const int d  = bd & (DINNER - 1);
  const float a = -__expf(Alog[d * NST + n]);
  float h = 0.f;
  for (int c = 0; c < NCH; ++c) {
    const int cidx = bd * NCH + c;
    float s = Ssum[cidx * NST + n];
    Hinit[cidx * NST + n] = h;                       // state at chunk start
    h = fmaf(__expf(a * Dsum[cidx]), h, s);          // chunk decay = exp(a * sum(delta))
  }
}

// ---------------------------------------------------------------- K4c: scan pass 2 + gating
__global__ __launch_bounds__(256) void k_scan3(const float* __restrict__ delta,
                                               const float* __restrict__ uc,
                                               const float* __restrict__ Bin,
                                               const float* __restrict__ Cin,
                                               const float* zin,               // aliases yout!
                                               const float* __restrict__ Alog,
                                               const float* __restrict__ Dvec,
                                               const float* __restrict__ Hinit,
                                               float* yout) {
  const int g = blockIdx.x * 256 + threadIdx.x;
  const int d    = g & (DINNER - 1);
  const int rest = g >> 9;
  const int c = rest & (NCH - 1);
  const int b = rest >> 7;
  __shared__ float Bsh[TCH][NST];
  __shared__ float Csh[TCH][NST];
  {
    const int base = (b * LSEQ + c * TCH) * NST;
    for (int v = threadIdx.x; v < TCH * NST; v += 256) {
      ((float*)Bsh)[v] = Bin[base + v];
      ((float*)Csh)[v] = Cin[base + v];
    }
  }
  __syncthreads();
  float a2[NST];
  #pragma unroll
  for (int n = 0; n < NST; ++n) a2[n] = -__expf(Alog[d * NST + n]) * LOG2E;
  const int cidx = (b * DINNER + d) * NCH + c;
  float h[NST];
  #pragma unroll
  for (int n = 0; n < NST; ++n) h[n] = Hinit[cidx * NST + n];
  const float Dd = Dvec[d];
  const int row0 = (b * LSEQ + c * TCH) * DINNER + d;
  for (int tt = 0; tt < TCH; ++tt) {
    float de = delta[row0 + tt * DINNER];
    float xv = uc[row0 + tt * DINNER];
    float du = de * xv;
    float y = 0.f;
    #pragma unroll
    for (int n = 0; n < NST; ++n) {
      float dA = exp2f(de * a2[n]);
      h[n] = fmaf(dA, h[n], du * Bsh[tt][n]);
      y = fmaf(h[n], Csh[tt][n], y);
    }
    float zz = zin[row0 + tt * DINNER];
    yout[row0 + tt * DINNER] = (y + xv * Dd) * fast_silu(zz);   // in-place over z: read-then-write same slot
  }
}

// ---------------------------------------------------------------- K5: out_proj + residual + LayerNorm (fused)
__global__ __launch_bounds__(256) void k_out(const float* __restrict__ yg,
                                             const float* __restrict__ X,
                                             const float* __restrict__ W,
                                             const float* __restrict__ gam,
                                             const float* __restrict__ bet,
                                             float* __restrict__ out) {
  __shared__ float Ys[16][512];
  __shared__ float Ws[16][256];
  const int t  = threadIdx.x;
  const int m0 = blockIdx.x * 16;
  for (int v = t; v < 2048; v += 256) {
    int r = v >> 7, c4 = v & 127;
    *(float4*)(&Ys[r][c4 * 4]) = *(const float4*)(yg + (m0 + r) * DINNER + c4 * 4);
  }
  const int tr = t >> 6, tn = t & 63;                 // wave tr owns rows tr*4..tr*4+3
  float acc[4][4] = {};
  for (int k0 = 0; k0 < DINNER; k0 += 16) {
    __syncthreads();
    for (int v = t; v < 1024; v += 256) {
      int r = v >> 6, c4 = v & 63;
      *(float4*)(&Ws[r][c4 * 4]) = *(const float4*)(W + (k0 + r) * DMODEL + c4 * 4);
    }
    __syncthreads();
    #pragma unroll
    for (int k = 0; k < 16; ++k) {
      float av[4];
      #pragma unroll
      for (int i = 0; i < 4; ++i) av[i] = Ys[tr * 4 + i][k0 + k];
      float4 bv = *(const float4*)(&Ws[k][tn * 4]);
      float bj[4] = {bv.x, bv.y, bv.z, bv.w};
      #pragma unroll
      for (int i = 0; i < 4; ++i)
        #pragma unroll
        for (int j = 0; j < 4; ++j) acc[i][j] = fmaf(av[i], bj[j], acc[i][j]);
    }
  }
  #pragma unroll
  for (int i = 0; i < 4; ++i) {
    const int m = m0 + tr * 4 + i;
    float v0 = acc[i][0] + X[m * DMODEL + tn * 4 + 0];
    float v1 = acc[i][1] + X[m * DMODEL + tn * 4 + 1];
    float v2 = acc[i][2] + X[m * DMODEL + tn * 4 + 2];
    float v3 = acc[i][3] + X[m * DMODEL + tn * 4 + 3];
    float s  = v0 + v1 + v2 + v3;
    float s2 = v0 * v0 + v1 * v1 + v2 * v2 + v3 * v3;
    #pragma unroll
    for (int off = 1; off < 64; off <<= 1) {
      s  += __shfl_xor(s,  off, 64);
      s2 += __shfl_xor(s2, off, 64);
    }
    float mu   = s * (1.f / 256.f);
    float var  = s2 * (1.f / 256.f) - mu * mu;
    float rstd = rsqrtf(var + 1e-5f);
    int n = tn * 4;
    float4 o;
    o.x = (v0 - mu) * rstd * gam[n + 0] + bet[n + 0];
    o.y = (v1 - mu) * rstd * gam[n + 1] + bet[n + 1];
    o.z = (v2 - mu) * rstd * gam[n + 2] + bet[n + 2];
    o.w = (v3 - mu) * rstd * gam[n + 3] + bet[n + 3];
    *(float4*)(out + m * DMODEL + n) = o;
  }
}

// ----------------------------------------------------------------
extern "C" void kernel_launch(void* const* d_in, const int* in_sizes, int n_in,
                              void* d_out, int out_size, void* d_ws, size_t ws_size,
                              hipStream_t stream) {
  const float* x    = (const float*)d_in[0];
  const float* ipw  = (const float*)d_in[1];
  const float* cw   = (const float*)d_in[2];
  const float* cb   = (const float*)d_in[3];
  const float* xpw  = (const float*)d_in[4];
  const float* dtw  = (const float*)d_in[5];
  const float* dtbv = (const float*)d_in[6];
  const float* alog = (const float*)d_in[7];
  const float* Dv   = (const float*)d_in[8];
  const float* opw  = (const float*)d_in[9];
  const float* gam  = (const float*)d_in[10];
  const float* bet  = (const float*)d_in[11];
  float* out = (float*)d_out;

  float* ws = (float*)d_ws;
  float* buf_u    = ws;                                    // [M, DINNER]; reused as delta after K2
  float* buf_z    = buf_u  + (size_t)MROWS * DINNER;       // [M, DINNER]; reused as ygate (in-place in K4c)
  float* buf_uc   = buf_z  + (size_t)MROWS * DINNER;       // [M, DINNER]
  float* buf_dt   = buf_uc + (size_t)MROWS * DINNER;       // [M, 16]
  float* buf_B    = buf_dt + (size_t)MROWS * NST;          // [M, 16]
  float* buf_C    = buf_B  + (size_t)MROWS * NST;          // [M, 16]
  float* buf_dsum = buf_C  + (size_t)MROWS * NST;          // [B*DINNER*NCH]
  float* buf_S    = buf_dsum + (size_t)BATCH * DINNER * NCH;        // [B*DINNER*NCH, 16]
  float* buf_H    = buf_S    + (size_t)BATCH * DINNER * NCH * NST;  // [B*DINNER*NCH, 16]

  k_inproj<<<dim3(2048), dim3(256), 0, stream>>>(x, ipw, buf_u, buf_z);
  k_conv  <<<dim3(MROWS * DINNER / 256), dim3(256), 0, stream>>>(buf_u, cw, cb, buf_uc);
  k_xproj <<<dim3(MROWS * 48 / 256), dim3(256), 0, stream>>>(buf_uc, xpw, buf_dt, buf_B, buf_C);
  k_delta <<<dim3(MROWS * DINNER / 256), dim3(256), 0, stream>>>(buf_dt, dtw, dtbv, buf_u);
  k_scan1 <<<dim3(BATCH * NCH * DINNER / 256), dim3(256), 0, stream>>>(buf_u, buf_uc, buf_B, alog, buf_S, buf_dsum);
  k_scan2 <<<dim3(BATCH * DINNER * NST / 256), dim3(256), 0, stream>>>(buf_S, buf_dsum, alog, buf_H);
  k_scan3 <<<dim3(BATCH * NCH * DINNER / 256), dim3(256), 0, stream>>>(buf_u, buf_uc, buf_B, buf_C, buf_z,
                                                                       alog, Dv, buf_H, buf_z);
  k_out   <<<dim3(MROWS / 16), dim3(256), 0, stream>>>(buf_z, x, opw, gam, bet, out);
}

// Round 2
// 196.446 us; speedup vs baseline: 1.4156x; 1.4156x over previous
//
#include <hip/hip_runtime.h>
#include <math.h>

constexpr int BATCH  = 2;
constexpr int LSEQ   = 4096;
constexpr int DMODEL = 256;
constexpr int DINNER = 512;
constexpr int NST    = 16;              // d_state
constexpr int MROWS  = BATCH * LSEQ;    // 8192
constexpr int NCH    = 128;             // chunks per sequence
constexpr int TCH    = LSEQ / NCH;      // 32 steps per chunk
constexpr float LOG2E = 1.44269504088896f;

typedef __attribute__((ext_vector_type(8))) short bf16x8;
typedef __attribute__((ext_vector_type(4))) float f32x4;

__device__ __forceinline__ float fast_silu(float v) { return v / (1.f + __expf(-v)); }

__device__ __forceinline__ unsigned short f2bf(float f) {
  unsigned int u = __float_as_uint(f);
  u = (u + 0x7fffu + ((u >> 16) & 1u)) >> 16;   // RNE
  return (unsigned short)u;
}

// ---------------------------------------------------------------- cast x -> bf16
__global__ __launch_bounds__(256) void k_cast_x(const float* __restrict__ x,
                                                unsigned short* __restrict__ xb) {
  int i = (blockIdx.x * 256 + threadIdx.x) * 4;
  float4 v = *(const float4*)(x + i);
  ushort4 o;
  o.x = f2bf(v.x); o.y = f2bf(v.y); o.z = f2bf(v.z); o.w = f2bf(v.w);
  *(ushort4*)(xb + i) = o;
}

// ---------------------------------------------------------------- transpose-cast W[K][N] -> Wt[N][K] bf16
__global__ __launch_bounds__(256) void k_castT(const float* __restrict__ W,
                                               unsigned short* __restrict__ Wt,
                                               int K, int N, int ktiles) {
  __shared__ float tile[32][33];
  const int bt = blockIdx.x;
  const int kt = bt % ktiles, nt = bt / ktiles;
  const int k0 = kt * 32, n0 = nt * 32;
  const int t = threadIdx.x;
  const int c = t & 31, r0 = t >> 5;
  #pragma unroll
  for (int it = 0; it < 4; ++it) {
    int r = r0 + it * 8;
    tile[r][c] = W[(size_t)(k0 + r) * N + n0 + c];
  }
  __syncthreads();
  #pragma unroll
  for (int it = 0; it < 4; ++it) {
    int cc = r0 + it * 8;                    // n within tile
    Wt[(size_t)(n0 + cc) * K + k0 + c] = f2bf(tile[c][cc]);
  }
}

// ---------------------------------------------------------------- K1: xz = x @ in_proj_w (bf16 MFMA), split u/z
// A = xb [8192][256] bf16, B = W1t [1024][256] bf16 (= in_proj_w^T)
__global__ __launch_bounds__(256) void k_inproj(const unsigned short* __restrict__ Xb,
                                                const unsigned short* __restrict__ Wt,
                                                float* __restrict__ u,
                                                float* __restrict__ z) {
  __shared__ unsigned short As[128][40];     // +16B pad: row stride 80B, 16B aligned
  __shared__ unsigned short Bs[128][40];
  const int t = threadIdx.x;
  const int m0 = (blockIdx.x & 63) * 128;    // M/128 = 64
  const int n0 = (blockIdx.x >> 6) * 128;    // N/128 = 8
  const int lane = t & 63, wid = t >> 6;
  const int hi = lane >> 4, l15 = lane & 15;
  const int wm = wid >> 1, wn = wid & 1;     // 2x2 waves, 64x64 each
  f32x4 zero = {0.f, 0.f, 0.f, 0.f};
  f32x4 acc[4][4];
  #pragma unroll
  for (int i = 0; i < 4; ++i)
    #pragma unroll
    for (int j = 0; j < 4; ++j) acc[i][j] = zero;

  for (int k0 = 0; k0 < DMODEL; k0 += 32) {
    __syncthreads();
    #pragma unroll
    for (int it = 0; it < 2; ++it) {
      int v = it * 256 + t;
      int r = v >> 2, part = v & 3;
      *(float4*)(&As[r][part * 8]) = *(const float4*)(Xb + (size_t)(m0 + r) * 256 + k0 + part * 8);
      *(float4*)(&Bs[r][part * 8]) = *(const float4*)(Wt + (size_t)(n0 + r) * 256 + k0 + part * 8);
    }
    __syncthreads();
    bf16x8 af[4], bfv[4];
    #pragma unroll
    for (int am = 0; am < 4; ++am) af[am] = *(const bf16x8*)(&As[wm * 64 + am * 16 + l15][hi * 8]);
    #pragma unroll
    for (int bn = 0; bn < 4; ++bn) bfv[bn] = *(const bf16x8*)(&Bs[wn * 64 + bn * 16 + l15][hi * 8]);
    #pragma unroll
    for (int am = 0; am < 4; ++am)
      #pragma unroll
      for (int bn = 0; bn < 4; ++bn)
        acc[am][bn] = __builtin_amdgcn_mfma_f32_16x16x32_bf16(af[am], bfv[bn], acc[am][bn], 0, 0, 0);
  }

  const bool isU = (n0 < DINNER);
  float* dst = isU ? u : z;
  const int nb = isU ? n0 : n0 - DINNER;
  #pragma unroll
  for (int am = 0; am < 4; ++am)
    #pragma unroll
    for (int j = 0; j < 4; ++j) {
      int m = m0 + wm * 64 + am * 16 + hi * 4 + j;
      #pragma unroll
      for (int bn = 0; bn < 4; ++bn) {
        int n = nb + wn * 64 + bn * 16 + l15;
        dst[(size_t)m * DINNER + n] = acc[am][bn][j];
      }
    }
}

// ---------------------------------------------------------------- K2: depthwise causal conv + SiLU
__global__ __launch_bounds__(256) void k_conv(const float* __restrict__ u,
                                              const float* __restrict__ cw,
                                              const float* __restrict__ cb,
                                              float* __restrict__ uc) {
  const int idx = blockIdx.x * 256 + threadIdx.x;
  const int d = idx & (DINNER - 1);
  const int m = idx >> 9;
  const int l = m & (LSEQ - 1);
  float acc = cb[d];
  #pragma unroll
  for (int j = 0; j < 4; ++j) {
    int lj = l + j - 3;
    float uu = (lj >= 0) ? u[idx + (j - 3) * DINNER] : 0.f;
    acc = fmaf(uu, cw[d * 4 + j], acc);
  }
  uc[idx] = fast_silu(acc);
}

// ---------------------------------------------------------------- K3a: dbl = u_conv @ x_proj_w -> dt,B,C
__global__ __launch_bounds__(256) void k_xproj(const float* __restrict__ uc,
                                               const float* __restrict__ xpw,
                                               float* __restrict__ dt_out,
                                               float* __restrict__ Bout,
                                               float* __restrict__ Cout) {
  const int idx = blockIdx.x * 256 + threadIdx.x;
  const int j = idx % 48;
  const int m = idx / 48;
  const float* row = uc + (size_t)m * DINNER;
  const float* wc  = xpw + j;
  float a0 = 0.f, a1 = 0.f, a2 = 0.f, a3 = 0.f;
  for (int k = 0; k < DINNER; k += 4) {
    a0 = fmaf(row[k + 0], wc[(k + 0) * 48], a0);
    a1 = fmaf(row[k + 1], wc[(k + 1) * 48], a1);
    a2 = fmaf(row[k + 2], wc[(k + 2) * 48], a2);
    a3 = fmaf(row[k + 3], wc[(k + 3) * 48], a3);
  }
  float acc = (a0 + a1) + (a2 + a3);
  if (j < 16)       dt_out[m * 16 + j]      = acc;
  else if (j < 32)  Bout[m * 16 + (j - 16)] = acc;
  else              Cout[m * 16 + (j - 32)] = acc;
}

// ---------------------------------------------------------------- K3b: delta = softplus(dt @ dt_proj_w + b)
__global__ __launch_bounds__(256) void k_delta(const float* __restrict__ dtin,
                                               const float* __restrict__ dtw,
                                               const float* __restrict__ dtbias,
                                               float* __restrict__ delta) {
  const int idx = blockIdx.x * 256 + threadIdx.x;
  const int d = idx & (DINNER - 1);
  const int m = idx >> 9;
  float acc = dtbias[d];
  const float* dr = dtin + m * 16;
  #pragma unroll
  for (int r = 0; r < 16; ++r) acc = fmaf(dr[r], dtw[r * DINNER + d], acc);
  delta[idx] = (acc > 20.f) ? acc : log1pf(__expf(acc));
}

// ---------------------------------------------------------------- K4a: chunked scan pass 1
__global__ __launch_bounds__(256) void k_scan1(const float* __restrict__ delta,
                                               const float* __restrict__ uc,
                                               const float* __restrict__ Bin,
                                               const float* __restrict__ Alog,
                                               float* __restrict__ Ssum,
                                               float* __restrict__ Dsum) {
  const int g = blockIdx.x * 256 + threadIdx.x;
  const int d    = g & (DINNER - 1);
  const int rest = g >> 9;
  const int c = rest & (NCH - 1);
  const int b = rest >> 7;
  __shared__ float Bsh[TCH][NST];
  {
    const int base = (b * LSEQ + c * TCH) * NST;
    for (int v = threadIdx.x; v < TCH * NST; v += 256) ((float*)Bsh)[v] = Bin[base + v];
  }
  __syncthreads();
  float a2[NST];
  #pragma unroll
  for (int n = 0; n < NST; ++n) a2[n] = -__expf(Alog[d * NST + n]) * LOG2E;
  float S[NST];
  #pragma unroll
  for (int n = 0; n < NST; ++n) S[n] = 0.f;
  float dsum = 0.f;
  const int row0 = (b * LSEQ + c * TCH) * DINNER + d;
  for (int tt = 0; tt < TCH; ++tt) {
    float de = delta[row0 + tt * DINNER];
    float xv = uc[row0 + tt * DINNER];
    float du = de * xv;
    dsum += de;
    #pragma unroll
    for (int n = 0; n < NST; ++n) {
      float dA = exp2f(de * a2[n]);
      S[n] = fmaf(dA, S[n], du * Bsh[tt][n]);
    }
  }
  const int cidx = (b * DINNER + d) * NCH + c;
  Dsum[cidx] = dsum;
  #pragma unroll
  for (int n = 0; n < NST; ++n) Ssum[cidx * NST + n] = S[n];
}

// ---------------------------------------------------------------- K4b: cross-chunk exclusive scan
__global__ void k_scan2(const float* __restrict__ Ssum,
                        const float* __restrict__ Dsum,
                        const float* __restrict__ Alog,
                        float* __restrict__ Hinit) {
  const int g = blockIdx.x * 256 + threadIdx.x;
  const int n  = g & (NST - 1);
  const int bd = g >> 4;
  const int d  = bd & (DINNER - 1);
  const float a = -__expf(Alog[d * NST + n]);
  float h = 0.f;
  for (int c = 0; c < NCH; ++c) {
    const int cidx = bd * NCH + c;
    float s = Ssum[cidx * NST + n];
    Hinit[cidx * NST + n] = h;
    h = fmaf(__expf(a * Dsum[cidx]), h, s);
  }
}

// ---------------------------------------------------------------- K4c: scan pass 2 + gating -> bf16 ygate
__global__ __launch_bounds__(256) void k_scan3(const float* __restrict__ delta,
                                               const float* __restrict__ uc,
                                               const float* __restrict__ Bin,
                                               const float* __restrict__ Cin,
                                               const float* __restrict__ zin,
                                               const float* __restrict__ Alog,
                                               const float* __restrict__ Dvec,
                                               const float* __restrict__ Hinit,
                                               unsigned short* __restrict__ ygb) {
  const int g = blockIdx.x * 256 + threadIdx.x;
  const int d    = g & (DINNER - 1);
  const int rest = g >> 9;
  const int c = rest & (NCH - 1);
  const int b = rest >> 7;
  __shared__ float Bsh[TCH][NST];
  __shared__ float Csh[TCH][NST];
  {
    const int base = (b * LSEQ + c * TCH) * NST;
    for (int v = threadIdx.x; v < TCH * NST; v += 256) {
      ((float*)Bsh)[v] = Bin[base + v];
      ((float*)Csh)[v] = Cin[base + v];
    }
  }
  __syncthreads();
  float a2[NST];
  #pragma unroll
  for (int n = 0; n < NST; ++n) a2[n] = -__expf(Alog[d * NST + n]) * LOG2E;
  const int cidx = (b * DINNER + d) * NCH + c;
  float h[NST];
  #pragma unroll
  for (int n = 0; n < NST; ++n) h[n] = Hinit[cidx * NST + n];
  const float Dd = Dvec[d];
  const int row0 = (b * LSEQ + c * TCH) * DINNER + d;
  for (int tt = 0; tt < TCH; ++tt) {
    float de = delta[row0 + tt * DINNER];
    float xv = uc[row0 + tt * DINNER];
    float du = de * xv;
    float y = 0.f;
    #pragma unroll
    for (int n = 0; n < NST; ++n) {
      float dA = exp2f(de * a2[n]);
      h[n] = fmaf(dA, h[n], du * Bsh[tt][n]);
      y = fmaf(h[n], Csh[tt][n], y);
    }
    float zz = zin[row0 + tt * DINNER];
    ygb[row0 + tt * DINNER] = f2bf((y + xv * Dd) * fast_silu(zz));
  }
}

// ---------------------------------------------------------------- K5: out_proj (bf16 MFMA) + residual + LayerNorm
// A = ygb [8192][512] bf16, B = W2t [256][512] bf16 (= out_proj_w^T). Tile 32x256, 8 waves.
__global__ __launch_bounds__(512) void k_out(const unsigned short* __restrict__ Yb,
                                             const unsigned short* __restrict__ W2t,
                                             const float* __restrict__ X,
                                             const float* __restrict__ gam,
                                             const float* __restrict__ bet,
                                             float* __restrict__ out) {
  __shared__ unsigned short As[32][40];
  __shared__ unsigned short Bs[256][40];
  __shared__ float red[4][32][2];
  const int t = threadIdx.x;
  const int m0 = blockIdx.x * 32;
  const int lane = t & 63, wid = t >> 6;           // 8 waves
  const int hi = lane >> 4, l15 = lane & 15;
  const int wm = wid >> 2, wn = wid & 3;           // 2x4: wave tile 16x64
  f32x4 zero = {0.f, 0.f, 0.f, 0.f};
  f32x4 acc[4];
  #pragma unroll
  for (int bn = 0; bn < 4; ++bn) acc[bn] = zero;

  for (int k0 = 0; k0 < DINNER; k0 += 32) {
    __syncthreads();
    if (t < 128) {
      int r = t >> 2, part = t & 3;
      *(float4*)(&As[r][part * 8]) = *(const float4*)(Yb + (size_t)(m0 + r) * 512 + k0 + part * 8);
    }
    #pragma unroll
    for (int it = 0; it < 2; ++it) {
      int v = it * 512 + t;
      int r = v >> 2, part = v & 3;
      *(float4*)(&Bs[r][part * 8]) = *(const float4*)(W2t + (size_t)r * 512 + k0 + part * 8);
    }
    __syncthreads();
    bf16x8 af = *(const bf16x8*)(&As[wm * 16 + l15][hi * 8]);
    #pragma unroll
    for (int bn = 0; bn < 4; ++bn) {
      bf16x8 bfr = *(const bf16x8*)(&Bs[wn * 64 + bn * 16 + l15][hi * 8]);
      acc[bn] = __builtin_amdgcn_mfma_f32_16x16x32_bf16(af, bfr, acc[bn], 0, 0, 0);
    }
  }

  // residual add + row stats
  float vv[4][4];
  float s[4] = {0.f, 0.f, 0.f, 0.f}, s2[4] = {0.f, 0.f, 0.f, 0.f};
  #pragma unroll
  for (int bn = 0; bn < 4; ++bn) {
    int n = wn * 64 + bn * 16 + l15;
    #pragma unroll
    for (int j = 0; j < 4; ++j) {
      int m = m0 + wm * 16 + hi * 4 + j;
      float v = acc[bn][j] + X[(size_t)m * DMODEL + n];
      vv[bn][j] = v;
      s[j] += v; s2[j] += v * v;
    }
  }
  #pragma unroll
  for (int j = 0; j < 4; ++j) {
    #pragma unroll
    for (int off = 1; off < 16; off <<= 1) {
      s[j]  += __shfl_xor(s[j],  off, 64);
      s2[j] += __shfl_xor(s2[j], off, 64);
    }
  }
  if (l15 == 0) {
    #pragma unroll
    for (int j = 0; j < 4; ++j) {
      red[wn][wm * 16 + hi * 4 + j][0] = s[j];
      red[wn][wm * 16 + hi * 4 + j][1] = s2[j];
    }
  }
  __syncthreads();
  float g[4], bb[4];
  #pragma unroll
  for (int bn = 0; bn < 4; ++bn) {
    int n = wn * 64 + bn * 16 + l15;
    g[bn] = gam[n]; bb[bn] = bet[n];
  }
  #pragma unroll
  for (int j = 0; j < 4; ++j) {
    int row = wm * 16 + hi * 4 + j;
    float S  = red[0][row][0] + red[1][row][0] + red[2][row][0] + red[3][row][0];
    float S2 = red[0][row][1] + red[1][row][1] + red[2][row][1] + red[3][row][1];
    float mu = S * (1.f / 256.f);
    float rstd = rsqrtf(S2 * (1.f / 256.f) - mu * mu + 1e-5f);
    int m = m0 + row;
    #pragma unroll
    for (int bn = 0; bn < 4; ++bn) {
      int n = wn * 64 + bn * 16 + l15;
      out[(size_t)m * DMODEL + n] = (vv[bn][j] - mu) * rstd * g[bn] + bb[bn];
    }
  }
}

// ----------------------------------------------------------------
extern "C" void kernel_launch(void* const* d_in, const int* in_sizes, int n_in,
                              void* d_out, int out_size, void* d_ws, size_t ws_size,
                              hipStream_t stream) {
  const float* x    = (const float*)d_in[0];
  const float* ipw  = (const float*)d_in[1];
  const float* cw   = (const float*)d_in[2];
  const float* cb   = (const float*)d_in[3];
  const float* xpw  = (const float*)d_in[4];
  const float* dtw  = (const float*)d_in[5];
  const float* dtbv = (const float*)d_in[6];
  const float* alog = (const float*)d_in[7];
  const float* Dv   = (const float*)d_in[8];
  const float* opw  = (const float*)d_in[9];
  const float* gam  = (const float*)d_in[10];
  const float* bet  = (const float*)d_in[11];
  float* out = (float*)d_out;

  float* ws = (float*)d_ws;
  float* buf_u    = ws;                                    // [M,512]; delta after k_delta
  float* buf_z    = buf_u  + (size_t)MROWS * DINNER;       // [M,512]
  float* buf_uc   = buf_z  + (size_t)MROWS * DINNER;       // [M,512]; first 4MB aliased by xb pre-conv
  unsigned short* xb = (unsigned short*)buf_uc;            // [M,256] bf16 (dead before k_conv writes uc)
  float* buf_dt   = buf_uc + (size_t)MROWS * DINNER;       // [M,16]
  float* buf_B    = buf_dt + (size_t)MROWS * NST;          // [M,16]
  float* buf_C    = buf_B  + (size_t)MROWS * NST;          // [M,16]
  float* buf_dsum = buf_C  + (size_t)MROWS * NST;          // [B*512*128]
  float* buf_S    = buf_dsum + (size_t)BATCH * DINNER * NCH;        // [B*512*128,16]
  unsigned short* ygb = (unsigned short*)buf_S;            // [M,512] bf16 (S dead after scan2)
  float* buf_H    = buf_S    + (size_t)BATCH * DINNER * NCH * NST;  // [B*512*128,16]
  unsigned short* W1t = (unsigned short*)(buf_H + (size_t)BATCH * DINNER * NCH * NST); // [1024,256] bf16
  unsigned short* W2t = W1t + (size_t)1024 * 256;          // [256,512] bf16

  k_cast_x<<<dim3(2048), dim3(256), 0, stream>>>(x, xb);
  k_castT <<<dim3(256),  dim3(256), 0, stream>>>(ipw, W1t, 256, 1024, 8);
  k_castT <<<dim3(128),  dim3(256), 0, stream>>>(opw, W2t, 512, 256, 16);
  k_inproj<<<dim3(512),  dim3(256), 0, stream>>>(xb, W1t, buf_u, buf_z);
  k_conv  <<<dim3(MROWS * DINNER / 256), dim3(256), 0, stream>>>(buf_u, cw, cb, buf_uc);
  k_xproj <<<dim3(MROWS * 48 / 256), dim3(256), 0, stream>>>(buf_uc, xpw, buf_dt, buf_B, buf_C);
  k_delta <<<dim3(MROWS * DINNER / 256), dim3(256), 0, stream>>>(buf_dt, dtw, dtbv, buf_u);
  k_scan1 <<<dim3(BATCH * NCH * DINNER / 256), dim3(256), 0, stream>>>(buf_u, buf_uc, buf_B, alog, buf_S, buf_dsum);
  k_scan2 <<<dim3(BATCH * DINNER * NST / 256), dim3(256), 0, stream>>>(buf_S, buf_dsum, alog, buf_H);
  k_scan3 <<<dim3(BATCH * NCH * DINNER / 256), dim3(256), 0, stream>>>(buf_u, buf_uc, buf_B, buf_C, buf_z,
                                                                       alog, Dv, buf_H, ygb);
  k_out   <<<dim3(MROWS / 32), dim3(512), 0, stream>>>(ygb, W2t, x, gam, bet, out);
}

// Round 3
// 159.006 us; speedup vs baseline: 1.7489x; 1.2355x over previous
//
#include <hip/hip_runtime.h>
#include <math.h>

constexpr int BATCH  = 2;
constexpr int LSEQ   = 4096;
constexpr int DMODEL = 256;
constexpr int DINNER = 512;
constexpr int NST    = 16;              // d_state
constexpr int MROWS  = BATCH * LSEQ;    // 8192
constexpr int NCH    = 128;             // chunks per sequence
constexpr int TCH    = LSEQ / NCH;      // 32 steps per chunk
constexpr float LOG2E = 1.44269504088896f;

typedef __attribute__((ext_vector_type(8))) short bf16x8;
typedef __attribute__((ext_vector_type(4))) float f32x4;

__device__ __forceinline__ float fast_silu(float v) { return v / (1.f + __expf(-v)); }

__device__ __forceinline__ unsigned short f2bf(float f) {
  unsigned int u = __float_as_uint(f);
  u = (u + 0x7fffu + ((u >> 16) & 1u)) >> 16;   // RNE
  return (unsigned short)u;
}
__device__ __forceinline__ float bf2f(unsigned short u) {
  return __uint_as_float(((unsigned int)u) << 16);
}

// ---------------------------------------------------------------- cast x -> bf16
__global__ __launch_bounds__(256) void k_cast_x(const float* __restrict__ x,
                                                unsigned short* __restrict__ xb) {
  int i = (blockIdx.x * 256 + threadIdx.x) * 4;
  float4 v = *(const float4*)(x + i);
  ushort4 o;
  o.x = f2bf(v.x); o.y = f2bf(v.y); o.z = f2bf(v.z); o.w = f2bf(v.w);
  *(ushort4*)(xb + i) = o;
}

// ---------------------------------------------------------------- transpose-cast W[K][N] -> Wt[N][K] bf16
__global__ __launch_bounds__(256) void k_castT(const float* __restrict__ W,
                                               unsigned short* __restrict__ Wt,
                                               int K, int N, int ktiles) {
  __shared__ float tile[32][33];
  const int bt = blockIdx.x;
  const int kt = bt % ktiles, nt = bt / ktiles;
  const int k0 = kt * 32, n0 = nt * 32;
  const int t = threadIdx.x;
  const int c = t & 31, r0 = t >> 5;
  #pragma unroll
  for (int it = 0; it < 4; ++it) {
    int r = r0 + it * 8;
    tile[r][c] = W[(size_t)(k0 + r) * N + n0 + c];
  }
  __syncthreads();
  #pragma unroll
  for (int it = 0; it < 4; ++it) {
    int cc = r0 + it * 8;
    Wt[(size_t)(n0 + cc) * K + k0 + c] = f2bf(tile[c][cc]);
  }
}

// ---------------------------------------------------------------- transpose-cast x_proj_w [512][48] -> [48][512] bf16
__global__ __launch_bounds__(256) void k_cast_xpw(const float* __restrict__ xpw,
                                                  unsigned short* __restrict__ xpT) {
  int idx = blockIdx.x * 256 + threadIdx.x;      // 48*512 = 24576
  int n = idx >> 9, k = idx & 511;
  xpT[n * 512 + k] = f2bf(xpw[k * 48 + n]);
}

// ---------------------------------------------------------------- K1: xz = x @ in_proj_w (bf16 MFMA); u fp32, z bf16
__global__ __launch_bounds__(256) void k_inproj(const unsigned short* __restrict__ Xb,
                                                const unsigned short* __restrict__ Wt,
                                                float* __restrict__ u,
                                                unsigned short* __restrict__ zb) {
  __shared__ unsigned short As[128][40];
  __shared__ unsigned short Bs[128][40];
  const int t = threadIdx.x;
  const int m0 = (blockIdx.x & 63) * 128;
  const int n0 = (blockIdx.x >> 6) * 128;
  const int lane = t & 63, wid = t >> 6;
  const int hi = lane >> 4, l15 = lane & 15;
  const int wm = wid >> 1, wn = wid & 1;
  f32x4 zero = {0.f, 0.f, 0.f, 0.f};
  f32x4 acc[4][4];
  #pragma unroll
  for (int i = 0; i < 4; ++i)
    #pragma unroll
    for (int j = 0; j < 4; ++j) acc[i][j] = zero;

  for (int k0 = 0; k0 < DMODEL; k0 += 32) {
    __syncthreads();
    #pragma unroll
    for (int it = 0; it < 2; ++it) {
      int v = it * 256 + t;
      int r = v >> 2, part = v & 3;
      *(float4*)(&As[r][part * 8]) = *(const float4*)(Xb + (size_t)(m0 + r) * 256 + k0 + part * 8);
      *(float4*)(&Bs[r][part * 8]) = *(const float4*)(Wt + (size_t)(n0 + r) * 256 + k0 + part * 8);
    }
    __syncthreads();
    bf16x8 af[4], bfv[4];
    #pragma unroll
    for (int am = 0; am < 4; ++am) af[am] = *(const bf16x8*)(&As[wm * 64 + am * 16 + l15][hi * 8]);
    #pragma unroll
    for (int bn = 0; bn < 4; ++bn) bfv[bn] = *(const bf16x8*)(&Bs[wn * 64 + bn * 16 + l15][hi * 8]);
    #pragma unroll
    for (int am = 0; am < 4; ++am)
      #pragma unroll
      for (int bn = 0; bn < 4; ++bn)
        acc[am][bn] = __builtin_amdgcn_mfma_f32_16x16x32_bf16(af[am], bfv[bn], acc[am][bn], 0, 0, 0);
  }

  if (n0 < DINNER) {
    #pragma unroll
    for (int am = 0; am < 4; ++am)
      #pragma unroll
      for (int j = 0; j < 4; ++j) {
        int m = m0 + wm * 64 + am * 16 + hi * 4 + j;
        #pragma unroll
        for (int bn = 0; bn < 4; ++bn) {
          int n = n0 + wn * 64 + bn * 16 + l15;
          u[(size_t)m * DINNER + n] = acc[am][bn][j];
        }
      }
  } else {
    #pragma unroll
    for (int am = 0; am < 4; ++am)
      #pragma unroll
      for (int j = 0; j < 4; ++j) {
        int m = m0 + wm * 64 + am * 16 + hi * 4 + j;
        #pragma unroll
        for (int bn = 0; bn < 4; ++bn) {
          int n = (n0 - DINNER) + wn * 64 + bn * 16 + l15;
          zb[(size_t)m * DINNER + n] = f2bf(acc[am][bn][j]);
        }
      }
  }
}

// ---------------------------------------------------------------- K2: depthwise causal conv + SiLU -> bf16
__global__ __launch_bounds__(256) void k_conv(const float* __restrict__ u,
                                              const float* __restrict__ cw,
                                              const float* __restrict__ cb,
                                              unsigned short* __restrict__ ucb) {
  const int idx = blockIdx.x * 256 + threadIdx.x;
  const int d = idx & (DINNER - 1);
  const int m = idx >> 9;
  const int l = m & (LSEQ - 1);
  float acc = cb[d];
  #pragma unroll
  for (int j = 0; j < 4; ++j) {
    int lj = l + j - 3;
    float uu = (lj >= 0) ? u[idx + (j - 3) * DINNER] : 0.f;
    acc = fmaf(uu, cw[d * 4 + j], acc);
  }
  ucb[idx] = f2bf(fast_silu(acc));
}

// ---------------------------------------------------------------- K3: dbl = uc @ x_proj_w via MFMA -> dt,B,C (fp32)
// A = ucb [8192][512] bf16, B = xpT [48][512] bf16. Tile 32 rows, 2 waves, grid 256.
__global__ __launch_bounds__(128) void k_xprojm(const unsigned short* __restrict__ ucb,
                                                const unsigned short* __restrict__ xpT,
                                                float* __restrict__ dt_out,
                                                float* __restrict__ Bout,
                                                float* __restrict__ Cout) {
  __shared__ unsigned short As[32][136];
  __shared__ unsigned short Bs[48][136];
  const int t = threadIdx.x;
  const int m0 = blockIdx.x * 32;
  const int lane = t & 63, wid = t >> 6;     // 2 waves
  const int hi = lane >> 4, l15 = lane & 15;
  f32x4 zero = {0.f, 0.f, 0.f, 0.f};
  f32x4 acc[3] = {zero, zero, zero};

  for (int k0 = 0; k0 < DINNER; k0 += 128) {
    __syncthreads();
    #pragma unroll
    for (int it = 0; it < 4; ++it) {         // A: 32 rows x 16 chunks
      int v = it * 128 + t;
      int r = v >> 4, part = v & 15;
      *(float4*)(&As[r][part * 8]) = *(const float4*)(ucb + (size_t)(m0 + r) * 512 + k0 + part * 8);
    }
    #pragma unroll
    for (int it = 0; it < 6; ++it) {         // B: 48 rows x 16 chunks
      int v = it * 128 + t;
      int r = v >> 4, part = v & 15;
      *(float4*)(&Bs[r][part * 8]) = *(const float4*)(xpT + (size_t)r * 512 + k0 + part * 8);
    }
    __syncthreads();
    #pragma unroll
    for (int kk = 0; kk < 4; ++kk) {
      bf16x8 af = *(const bf16x8*)(&As[wid * 16 + l15][kk * 32 + hi * 8]);
      #pragma unroll
      for (int nf = 0; nf < 3; ++nf) {
        bf16x8 bv = *(const bf16x8*)(&Bs[nf * 16 + l15][kk * 32 + hi * 8]);
        acc[nf] = __builtin_amdgcn_mfma_f32_16x16x32_bf16(af, bv, acc[nf], 0, 0, 0);
      }
    }
  }
  #pragma unroll
  for (int j = 0; j < 4; ++j) {
    int m = m0 + wid * 16 + hi * 4 + j;
    dt_out[m * 16 + l15] = acc[0][j];
    Bout[m * 16 + l15]   = acc[1][j];
    Cout[m * 16 + l15]   = acc[2][j];
  }
}

// ---------------------------------------------------------------- K4a: chunked scan pass 1 (delta recomputed in-kernel)
__global__ __launch_bounds__(256) void k_scan1(const unsigned short* __restrict__ ucb,
                                               const float* __restrict__ dtin,
                                               const float* __restrict__ dtw,
                                               const float* __restrict__ dtb,
                                               const float* __restrict__ Bin,
                                               const float* __restrict__ Alog,
                                               float* __restrict__ Ssum,
                                               float* __restrict__ Dsum) {
  const int g = blockIdx.x * 256 + threadIdx.x;
  const int d    = g & (DINNER - 1);
  const int rest = g >> 9;
  const int c = rest & (NCH - 1);
  const int b = rest >> 7;
  __shared__ float Bsh[TCH][NST];
  __shared__ float dtsh[TCH][NST];
  {
    const int base = (b * LSEQ + c * TCH) * NST;
    for (int v = threadIdx.x; v < TCH * NST; v += 256) {
      ((float*)Bsh)[v]  = Bin[base + v];
      ((float*)dtsh)[v] = dtin[base + v];
    }
  }
  __syncthreads();
  float dwreg[NST];
  #pragma unroll
  for (int r = 0; r < NST; ++r) dwreg[r] = dtw[r * DINNER + d];
  const float bias = dtb[d];
  float a2[NST];
  #pragma unroll
  for (int n = 0; n < NST; ++n) a2[n] = -__expf(Alog[d * NST + n]) * LOG2E;
  float S[NST];
  #pragma unroll
  for (int n = 0; n < NST; ++n) S[n] = 0.f;
  float dsum = 0.f;
  const int row0 = (b * LSEQ + c * TCH) * DINNER + d;
  for (int tt = 0; tt < TCH; ++tt) {
    float acc = bias;
    #pragma unroll
    for (int r = 0; r < NST; ++r) acc = fmaf(dtsh[tt][r], dwreg[r], acc);
    float de = (acc > 20.f) ? acc : log1pf(__expf(acc));
    float xv = bf2f(ucb[row0 + tt * DINNER]);
    float du = de * xv;
    dsum += de;
    #pragma unroll
    for (int n = 0; n < NST; ++n) {
      float dA = exp2f(de * a2[n]);
      S[n] = fmaf(dA, S[n], du * Bsh[tt][n]);
    }
  }
  const int cidx = (b * DINNER + d) * NCH + c;
  Dsum[cidx] = dsum;
  #pragma unroll
  for (int n = 0; n < NST; ++n) Ssum[cidx * NST + n] = S[n];
}

// ---------------------------------------------------------------- K4b: cross-chunk exclusive scan
__global__ void k_scan2(const float* __restrict__ Ssum,
                        const float* __restrict__ Dsum,
                        const float* __restrict__ Alog,
                        float* __restrict__ Hinit) {
  const int g = blockIdx.x * 256 + threadIdx.x;
  const int n  = g & (NST - 1);
  const int bd = g >> 4;
  const int d  = bd & (DINNER - 1);
  const float a = -__expf(Alog[d * NST + n]);
  float h = 0.f;
  for (int c = 0; c < NCH; ++c) {
    const int cidx = bd * NCH + c;
    float s = Ssum[cidx * NST + n];
    Hinit[cidx * NST + n] = h;
    h = fmaf(__expf(a * Dsum[cidx]), h, s);
  }
}

// ---------------------------------------------------------------- K4c: scan pass 2 + gating -> bf16 ygate
__global__ __launch_bounds__(256) void k_scan3(const unsigned short* __restrict__ ucb,
                                               const float* __restrict__ dtin,
                                               const float* __restrict__ dtw,
                                               const float* __restrict__ dtb,
                                               const float* __restrict__ Bin,
                                               const float* __restrict__ Cin,
                                               const unsigned short* __restrict__ zb,
                                               const float* __restrict__ Alog,
                                               const float* __restrict__ Dvec,
                                               const float* __restrict__ Hinit,
                                               unsigned short* __restrict__ ygb) {
  const int g = blockIdx.x * 256 + threadIdx.x;
  const int d    = g & (DINNER - 1);
  const int rest = g >> 9;
  const int c = rest & (NCH - 1);
  const int b = rest >> 7;
  __shared__ float Bsh[TCH][NST];
  __shared__ float Csh[TCH][NST];
  __shared__ float dtsh[TCH][NST];
  {
    const int base = (b * LSEQ + c * TCH) * NST;
    for (int v = threadIdx.x; v < TCH * NST; v += 256) {
      ((float*)Bsh)[v]  = Bin[base + v];
      ((float*)Csh)[v]  = Cin[base + v];
      ((float*)dtsh)[v] = dtin[base + v];
    }
  }
  __syncthreads();
  float dwreg[NST];
  #pragma unroll
  for (int r = 0; r < NST; ++r) dwreg[r] = dtw[r * DINNER + d];
  const float bias = dtb[d];
  float a2[NST];
  #pragma unroll
  for (int n = 0; n < NST; ++n) a2[n] = -__expf(Alog[d * NST + n]) * LOG2E;
  const int cidx = (b * DINNER + d) * NCH + c;
  float h[NST];
  #pragma unroll
  for (int n = 0; n < NST; ++n) h[n] = Hinit[cidx * NST + n];
  const float Dd = Dvec[d];
  const int row0 = (b * LSEQ + c * TCH) * DINNER + d;
  for (int tt = 0; tt < TCH; ++tt) {
    float acc = bias;
    #pragma unroll
    for (int r = 0; r < NST; ++r) acc = fmaf(dtsh[tt][r], dwreg[r], acc);
    float de = (acc > 20.f) ? acc : log1pf(__expf(acc));
    float xv = bf2f(ucb[row0 + tt * DINNER]);
    float du = de * xv;
    float y = 0.f;
    #pragma unroll
    for (int n = 0; n < NST; ++n) {
      float dA = exp2f(de * a2[n]);
      h[n] = fmaf(dA, h[n], du * Bsh[tt][n]);
      y = fmaf(h[n], Csh[tt][n], y);
    }
    float zz = bf2f(zb[row0 + tt * DINNER]);
    ygb[row0 + tt * DINNER] = f2bf((y + xv * Dd) * fast_silu(zz));
  }
}

// ---------------------------------------------------------------- K5: out_proj (bf16 MFMA) + residual + LayerNorm
__global__ __launch_bounds__(512) void k_out(const unsigned short* __restrict__ Yb,
                                             const unsigned short* __restrict__ W2t,
                                             const float* __restrict__ X,
                                             const float* __restrict__ gam,
                                             const float* __restrict__ bet,
                                             float* __restrict__ out) {
  __shared__ unsigned short As[32][40];
  __shared__ unsigned short Bs[256][40];
  __shared__ float red[4][32][2];
  const int t = threadIdx.x;
  const int m0 = blockIdx.x * 32;
  const int lane = t & 63, wid = t >> 6;
  const int hi = lane >> 4, l15 = lane & 15;
  const int wm = wid >> 2, wn = wid & 3;
  f32x4 zero = {0.f, 0.f, 0.f, 0.f};
  f32x4 acc[4];
  #pragma unroll
  for (int bn = 0; bn < 4; ++bn) acc[bn] = zero;

  for (int k0 = 0; k0 < DINNER; k0 += 32) {
    __syncthreads();
    if (t < 128) {
      int r = t >> 2, part = t & 3;
      *(float4*)(&As[r][part * 8]) = *(const float4*)(Yb + (size_t)(m0 + r) * 512 + k0 + part * 8);
    }
    #pragma unroll
    for (int it = 0; it < 2; ++it) {
      int v = it * 512 + t;
      int r = v >> 2, part = v & 3;
      *(float4*)(&Bs[r][part * 8]) = *(const float4*)(W2t + (size_t)r * 512 + k0 + part * 8);
    }
    __syncthreads();
    bf16x8 af = *(const bf16x8*)(&As[wm * 16 + l15][hi * 8]);
    #pragma unroll
    for (int bn = 0; bn < 4; ++bn) {
      bf16x8 bfr = *(const bf16x8*)(&Bs[wn * 64 + bn * 16 + l15][hi * 8]);
      acc[bn] = __builtin_amdgcn_mfma_f32_16x16x32_bf16(af, bfr, acc[bn], 0, 0, 0);
    }
  }

  float vv[4][4];
  float s[4] = {0.f, 0.f, 0.f, 0.f}, s2[4] = {0.f, 0.f, 0.f, 0.f};
  #pragma unroll
  for (int bn = 0; bn < 4; ++bn) {
    int n = wn * 64 + bn * 16 + l15;
    #pragma unroll
    for (int j = 0; j < 4; ++j) {
      int m = m0 + wm * 16 + hi * 4 + j;
      float v = acc[bn][j] + X[(size_t)m * DMODEL + n];
      vv[bn][j] = v;
      s[j] += v; s2[j] += v * v;
    }
  }
  #pragma unroll
  for (int j = 0; j < 4; ++j) {
    #pragma unroll
    for (int off = 1; off < 16; off <<= 1) {
      s[j]  += __shfl_xor(s[j],  off, 64);
      s2[j] += __shfl_xor(s2[j], off, 64);
    }
  }
  if (l15 == 0) {
    #pragma unroll
    for (int j = 0; j < 4; ++j) {
      red[wn][wm * 16 + hi * 4 + j][0] = s[j];
      red[wn][wm * 16 + hi * 4 + j][1] = s2[j];
    }
  }
  __syncthreads();
  float g[4], bb[4];
  #pragma unroll
  for (int bn = 0; bn < 4; ++bn) {
    int n = wn * 64 + bn * 16 + l15;
    g[bn] = gam[n]; bb[bn] = bet[n];
  }
  #pragma unroll
  for (int j = 0; j < 4; ++j) {
    int row = wm * 16 + hi * 4 + j;
    float S  = red[0][row][0] + red[1][row][0] + red[2][row][0] + red[3][row][0];
    float S2 = red[0][row][1] + red[1][row][1] + red[2][row][1] + red[3][row][1];
    float mu = S * (1.f / 256.f);
    float rstd = rsqrtf(S2 * (1.f / 256.f) - mu * mu + 1e-5f);
    int m = m0 + row;
    #pragma unroll
    for (int bn = 0; bn < 4; ++bn) {
      int n = wn * 64 + bn * 16 + l15;
      out[(size_t)m * DMODEL + n] = (vv[bn][j] - mu) * rstd * g[bn] + bb[bn];
    }
  }
}

// ----------------------------------------------------------------
extern "C" void kernel_launch(void* const* d_in, const int* in_sizes, int n_in,
                              void* d_out, int out_size, void* d_ws, size_t ws_size,
                              hipStream_t stream) {
  const float* x    = (const float*)d_in[0];
  const float* ipw  = (const float*)d_in[1];
  const float* cw   = (const float*)d_in[2];
  const float* cb   = (const float*)d_in[3];
  const float* xpw  = (const float*)d_in[4];
  const float* dtw  = (const float*)d_in[5];
  const float* dtbv = (const float*)d_in[6];
  const float* alog = (const float*)d_in[7];
  const float* Dv   = (const float*)d_in[8];
  const float* opw  = (const float*)d_in[9];
  const float* gam  = (const float*)d_in[10];
  const float* bet  = (const float*)d_in[11];
  float* out = (float*)d_out;

  char* ws = (char*)d_ws;
  float* buf_u  = (float*)ws;                                   // [M,512] fp32 (16MB)
  ws += (size_t)MROWS * DINNER * 4;
  unsigned short* zb  = (unsigned short*)ws;                    // [M,512] bf16 (8MB)
  ws += (size_t)MROWS * DINNER * 2;
  unsigned short* ucb = (unsigned short*)ws;                    // [M,512] bf16 (8MB)
  ws += (size_t)MROWS * DINNER * 2;
  unsigned short* xb  = (unsigned short*)ws;                    // [M,256] bf16 (4MB)
  ws += (size_t)MROWS * DMODEL * 2;
  float* buf_dt = (float*)ws;  ws += (size_t)MROWS * NST * 4;   // [M,16]
  float* buf_B  = (float*)ws;  ws += (size_t)MROWS * NST * 4;
  float* buf_C  = (float*)ws;  ws += (size_t)MROWS * NST * 4;
  float* buf_dsum = (float*)ws; ws += (size_t)BATCH * DINNER * NCH * 4;
  float* buf_S  = (float*)ws;  ws += (size_t)BATCH * DINNER * NCH * NST * 4;
  float* buf_H  = (float*)ws;  ws += (size_t)BATCH * DINNER * NCH * NST * 4;
  unsigned short* ygb = (unsigned short*)buf_S;                 // alias: S dead after scan2
  unsigned short* W1t = (unsigned short*)ws; ws += (size_t)1024 * 256 * 2;
  unsigned short* W2t = (unsigned short*)ws; ws += (size_t)256 * 512 * 2;
  unsigned short* xpT = (unsigned short*)ws; ws += (size_t)48 * 512 * 2;

  k_cast_x  <<<dim3(2048), dim3(256), 0, stream>>>(x, xb);
  k_castT   <<<dim3(256),  dim3(256), 0, stream>>>(ipw, W1t, 256, 1024, 8);
  k_castT   <<<dim3(128),  dim3(256), 0, stream>>>(opw, W2t, 512, 256, 16);
  k_cast_xpw<<<dim3(96),   dim3(256), 0, stream>>>(xpw, xpT);
  k_inproj  <<<dim3(512),  dim3(256), 0, stream>>>(xb, W1t, buf_u, zb);
  k_conv    <<<dim3(MROWS * DINNER / 256), dim3(256), 0, stream>>>(buf_u, cw, cb, ucb);
  k_xprojm  <<<dim3(MROWS / 32), dim3(128), 0, stream>>>(ucb, xpT, buf_dt, buf_B, buf_C);
  k_scan1   <<<dim3(BATCH * NCH * DINNER / 256), dim3(256), 0, stream>>>(ucb, buf_dt, dtw, dtbv, buf_B,
                                                                         alog, buf_S, buf_dsum);
  k_scan2   <<<dim3(BATCH * DINNER * NST / 256), dim3(256), 0, stream>>>(buf_S, buf_dsum, alog, buf_H);
  k_scan3   <<<dim3(BATCH * NCH * DINNER / 256), dim3(256), 0, stream>>>(ucb, buf_dt, dtw, dtbv, buf_B, buf_C,
                                                                         zb, alog, Dv, buf_H, ygb);
  k_out     <<<dim3(MROWS / 32), dim3(512), 0, stream>>>(ygb, W2t, x, gam, bet, out);
}